// Round 5
// baseline (219.068 us; speedup 1.0000x reference)
//
#include <hip/hip_runtime.h>

#define CIN    128
#define HH     56
#define WW_    56
#define NBATCH 32
#define COUT   256
#define KTOT   1152          // 9 taps * 128 ci  (k-order: kh, kw, ci)
#define PLANE  3136          // 56*56
#define HP     58            // padded H/W
#define BM     128           // c_out tile
#define BN     128           // pixel tile
#define BKS    32            // ci per K-step (36 steps; order = tap, ci asc)
#define NSTEP  36
#define NXROWS (NBATCH * HP) // 1856 x-prep blocks

#define WB_OFF   0                         // bf16 weights [256][9][128] in ws
#define XP_OFF   (1u << 20)                // padded bf16 input [32][58][58][128]

typedef __attribute__((ext_vector_type(8))) short bf16x8;
typedef __attribute__((ext_vector_type(4))) float f32x4;

__device__ __forceinline__ unsigned short f2bf(float f) {
    unsigned int u = __builtin_bit_cast(unsigned int, f);
    u += 0x7fffu + ((u >> 16) & 1u);   // RNE
    return (unsigned short)(u >> 16);
}

__device__ __forceinline__ void gl_lds16(const void* g, void* l) {
    __builtin_amdgcn_global_load_lds(
        (const __attribute__((address_space(1))) void*)g,
        (__attribute__((address_space(3))) void*)l, 16, 0, 0);
}

// ---- fused pre-pass (unchanged from round 4): blocks [0,1856) input rows,
// blocks [1856,2112) weights. ----
__global__ __launch_bounds__(256)
void prep(const float* __restrict__ in, const float* __restrict__ w,
          unsigned short* __restrict__ xp, unsigned short* __restrict__ wb) {
    __shared__ __align__(16) unsigned short Lx[16 * 456];   // 14592 B
    __shared__ __align__(16) unsigned short Lw[KTOT];       //  2304 B

    const int b = blockIdx.x;
    const int t = threadIdx.x;

    if (b >= NXROWS) {
        const int o = b - NXROWS;
        const float4* src = (const float4*)(w + (size_t)o * KTOT);   // 288 float4
        #pragma unroll
        for (int e = 0; e < 2; ++e) {
            const int q = t + e * 256;
            if (q < 288) {
                const float4 v = src[q];
                #pragma unroll
                for (int u = 0; u < 4; ++u) {
                    const int idx = q * 4 + u;       // = ci*9 + tap
                    const int ci  = idx / 9;
                    const int tap = idx - ci * 9;
                    Lw[tap * 128 + ci] = f2bf(((const float*)&v)[u]);
                }
            }
        }
        __syncthreads();
        if (t < 144)
            ((uint4*)(wb + (size_t)o * KTOT))[t] = ((const uint4*)Lw)[t];
        return;
    }

    const int n  = b / HP;
    const int ho = b - n * HP;
    uint4* orow = (uint4*)(xp + (((size_t)n * HP + ho) * HP) * CIN);  // 928 uint4

    if (ho == 0 || ho == HP - 1) {
        #pragma unroll
        for (int e = 0; e < 4; ++e) {
            const int idx = t + e * 256;
            if (idx < 928) orow[idx] = (uint4){0u, 0u, 0u, 0u};
        }
        return;
    }

    const int h = ho - 1;
    {
        const int ci = t >> 1;                       // 0..127
        const int w0 = (t & 1) * 28;                 // two half-rows
        const float4* ib = (const float4*)(in + ((size_t)n * CIN + ci) * PLANE
                                              + (size_t)h * WW_ + w0);
        unsigned short* Lp = &Lx[(ci >> 3) * 456 + w0 * 8 + (ci & 7)];
        #pragma unroll
        for (int q = 0; q < 7; ++q) {                // 7 x float4 = 28 floats
            const float4 v = ib[q];
            Lp[(q * 4 + 0) * 8] = f2bf(v.x);
            Lp[(q * 4 + 1) * 8] = f2bf(v.y);
            Lp[(q * 4 + 2) * 8] = f2bf(v.z);
            Lp[(q * 4 + 3) * 8] = f2bf(v.w);
        }
    }
    __syncthreads();

    #pragma unroll
    for (int e = 0; e < 4; ++e) {
        const int idx = t + e * 256;                 // uint4 index within row
        if (idx < 928) {
            const int wo = idx >> 4;                 // pixel 0..57
            const int ch = idx & 15;                 // 8-ci chunk
            uint4 pk = (uint4){0u, 0u, 0u, 0u};
            if (wo >= 1 && wo <= WW_)
                pk = *(const uint4*)&Lx[ch * 456 + (wo - 1) * 8];  // 16B-aligned
            orow[idx] = pk;
        }
    }
}

// ---- main conv: round-0 loop structure, BKS=32 -> 16 KB LDS/block so ~3x
// more independent blocks co-reside (m114 implicit overlap hides the barrier
// drain). Tile storage = 128B lines (2 rows/line), slot = (half*4+chunk) ^
// (line&7): linear gl_lds dest, uniform 2-way bank aliasing (free) on
// ds_read_b128. K order (tap, ci asc) identical to round 0 -> bit-identical. ----
__global__ __launch_bounds__(256, 4)
void conv_mfma(const unsigned short* __restrict__ wb,
               const unsigned short* __restrict__ xp,
               const float* __restrict__ bias,
               float* __restrict__ out)
{
    __shared__ __align__(16) unsigned short Asm_[BM * BKS];  // 8 KB
    __shared__ __align__(16) unsigned short Bsm_[BN * BKS];  // 8 KB

    const int t    = threadIdx.x;
    const int pix0 = blockIdx.x * BN;
    const int c0   = blockIdx.y * BM;

    // staging map: unit u (0..511, 2/thread): line=u>>3, phys slot p=u&7,
    // logical us = p ^ (line&7), row = 2*line + (us>>2), chunk = us&3.
    const char* aS[2]; const char* bS[2]; int dst[2];
    #pragma unroll
    for (int e = 0; e < 2; ++e) {
        const int u    = t + e * 256;
        const int line = u >> 3;
        const int us   = (u & 7) ^ (line & 7);
        const int row  = 2 * line + (us >> 2);
        const int ch   = us & 3;
        aS[e] = (const char*)wb + (size_t)(c0 + row) * (KTOT * 2) + ch * 16;
        const int pix = pix0 + row;
        const int n   = pix / PLANE;
        const int rem = pix - n * PLANE;
        const int h   = rem / WW_;
        const int w   = rem - h * WW_;
        bS[e] = (const char*)xp + ((size_t)(n * HP + h) * HP + w) * (CIN * 2) + ch * 16;
        dst[e] = u * 16;
    }

    const int lane = t & 63;
    const int wave = t >> 6;
    const int wm   = (wave & 1) * 64;
    const int wn   = (wave >> 1) * 64;
    const int lr   = lane & 15;
    const int quad = lane >> 4;

    // fragment read offsets (loop-invariant), swizzle-matched to staging map
    int offA[4], offB[4];
    #pragma unroll
    for (int i = 0; i < 4; ++i) {
        const int ra = wm + i * 16 + lr;
        offA[i] = (ra >> 1) * 128 + ((((ra & 1) * 4 + quad) ^ ((ra >> 1) & 7)) * 16);
        const int rb = wn + i * 16 + lr;
        offB[i] = (rb >> 1) * 128 + ((((rb & 1) * 4 + quad) ^ ((rb >> 1) & 7)) * 16);
    }

    f32x4 acc[4][4];
    #pragma unroll
    for (int i = 0; i < 4; ++i)
        #pragma unroll
        for (int j = 0; j < 4; ++j)
            acc[i][j] = (f32x4){0.f, 0.f, 0.f, 0.f};

    char* const asmb = (char*)Asm_;
    char* const bsmb = (char*)Bsm_;

    for (int hi = 0; hi < NSTEP; ++hi) {
        const int tap  = hi >> 2;
        const int aoff = hi * 64;                    // tap*256 + q*64
        const int boff = ((tap / 3) * HP + (tap % 3)) * (CIN * 2) + (hi & 3) * 64;
        gl_lds16(aS[0] + aoff, asmb + dst[0]);
        gl_lds16(aS[1] + aoff, asmb + dst[1]);
        gl_lds16(bS[0] + boff, bsmb + dst[0]);
        gl_lds16(bS[1] + boff, bsmb + dst[1]);
        __syncthreads();

        bf16x8 af[4], bfr[4];
        #pragma unroll
        for (int i = 0; i < 4; ++i) af[i]  = *(const bf16x8*)(asmb + offA[i]);
        #pragma unroll
        for (int j = 0; j < 4; ++j) bfr[j] = *(const bf16x8*)(bsmb + offB[j]);
        #pragma unroll
        for (int i = 0; i < 4; ++i)
            #pragma unroll
            for (int j = 0; j < 4; ++j)
                acc[i][j] = __builtin_amdgcn_mfma_f32_16x16x32_bf16(af[i], bfr[j], acc[i][j], 0, 0, 0);
        __syncthreads();
    }

    #pragma unroll
    for (int j = 0; j < 4; ++j) {
        const int pg    = pix0 + wn + j * 16 + lr;
        const int ni    = pg / PLANE;
        const int inner = pg - ni * PLANE;
        float* op = out + (size_t)ni * (COUT * PLANE) + inner;
        #pragma unroll
        for (int i = 0; i < 4; ++i) {
            const int crow = c0 + wm + i * 16 + quad * 4;
            #pragma unroll
            for (int r = 0; r < 4; ++r)
                op[(size_t)(crow + r) * PLANE] = acc[i][j][r] + bias[crow + r];
        }
    }
}

extern "C" void kernel_launch(void* const* d_in, const int* in_sizes, int n_in,
                              void* d_out, int out_size, void* d_ws, size_t ws_size,
                              hipStream_t stream) {
    const float* in   = (const float*)d_in[0];
    const float* wt   = (const float*)d_in[1];
    const float* bias = (const float*)d_in[2];
    float* out        = (float*)d_out;

    unsigned short* wb = (unsigned short*)((char*)d_ws + WB_OFF);
    unsigned short* xp = (unsigned short*)((char*)d_ws + XP_OFF);

    prep<<<NXROWS + COUT, 256, 0, stream>>>(in, wt, xp, wb);

    dim3 grid((NBATCH * PLANE) / BN, COUT / BM);
    conv_mfma<<<grid, 256, 0, stream>>>(wb, xp, bias, out);
}

// Round 6
// 201.533 us; speedup vs baseline: 1.0870x; 1.0870x over previous
//
#include <hip/hip_runtime.h>

#define CIN    128
#define HH     56
#define WW_    56
#define NBATCH 32
#define COUT   256
#define KTOT   1152          // 9 taps * 128 ci  (k-order: kh, kw, ci)
#define PLANE  3136          // 56*56
#define HP     58            // padded H/W
#define BM     128           // c_out tile
#define BN     128           // pixel tile
#define BK     64            // k per step (always within one tap: 1152 = 9*128)
#define NXROWS (NBATCH * HP) // 1856 x-prep blocks
#define NWG    ((NBATCH * PLANE / BN) * (COUT / BM))   // 1568, % 8 == 0
#define CHUNK  (NWG / 8)                               // 196 logical ids per XCD

#define WB_OFF   0                         // bf16 weights [256][9][128] in ws
#define XP_OFF   (1u << 20)                // padded bf16 input [32][58][58][128]

typedef __attribute__((ext_vector_type(8))) short bf16x8;
typedef __attribute__((ext_vector_type(4))) float f32x4;

__device__ __forceinline__ unsigned short f2bf(float f) {
    unsigned int u = __builtin_bit_cast(unsigned int, f);
    u += 0x7fffu + ((u >> 16) & 1u);   // RNE
    return (unsigned short)(u >> 16);
}

__device__ __forceinline__ void gl_lds16(const void* g, void* l) {
    __builtin_amdgcn_global_load_lds(
        (const __attribute__((address_space(1))) void*)g,
        (__attribute__((address_space(3))) void*)l, 16, 0, 0);
}

// ---- fused pre-pass (unchanged, verified): blocks [0,1856) input rows,
// blocks [1856,2112) weights. ----
__global__ __launch_bounds__(256)
void prep(const float* __restrict__ in, const float* __restrict__ w,
          unsigned short* __restrict__ xp, unsigned short* __restrict__ wb) {
    __shared__ __align__(16) unsigned short Lx[16 * 456];   // 14592 B
    __shared__ __align__(16) unsigned short Lw[KTOT];       //  2304 B

    const int b = blockIdx.x;
    const int t = threadIdx.x;

    if (b >= NXROWS) {
        const int o = b - NXROWS;
        const float4* src = (const float4*)(w + (size_t)o * KTOT);   // 288 float4
        #pragma unroll
        for (int e = 0; e < 2; ++e) {
            const int q = t + e * 256;
            if (q < 288) {
                const float4 v = src[q];
                #pragma unroll
                for (int u = 0; u < 4; ++u) {
                    const int idx = q * 4 + u;       // = ci*9 + tap
                    const int ci  = idx / 9;
                    const int tap = idx - ci * 9;
                    Lw[tap * 128 + ci] = f2bf(((const float*)&v)[u]);
                }
            }
        }
        __syncthreads();
        if (t < 144)
            ((uint4*)(wb + (size_t)o * KTOT))[t] = ((const uint4*)Lw)[t];
        return;
    }

    const int n  = b / HP;
    const int ho = b - n * HP;
    uint4* orow = (uint4*)(xp + (((size_t)n * HP + ho) * HP) * CIN);  // 928 uint4

    if (ho == 0 || ho == HP - 1) {
        #pragma unroll
        for (int e = 0; e < 4; ++e) {
            const int idx = t + e * 256;
            if (idx < 928) orow[idx] = (uint4){0u, 0u, 0u, 0u};
        }
        return;
    }

    const int h = ho - 1;
    {
        const int ci = t >> 1;                       // 0..127
        const int w0 = (t & 1) * 28;                 // two half-rows
        const float4* ib = (const float4*)(in + ((size_t)n * CIN + ci) * PLANE
                                              + (size_t)h * WW_ + w0);
        unsigned short* Lp = &Lx[(ci >> 3) * 456 + w0 * 8 + (ci & 7)];
        #pragma unroll
        for (int q = 0; q < 7; ++q) {                // 7 x float4 = 28 floats
            const float4 v = ib[q];
            Lp[(q * 4 + 0) * 8] = f2bf(v.x);
            Lp[(q * 4 + 1) * 8] = f2bf(v.y);
            Lp[(q * 4 + 2) * 8] = f2bf(v.z);
            Lp[(q * 4 + 3) * 8] = f2bf(v.w);
        }
    }
    __syncthreads();

    #pragma unroll
    for (int e = 0; e < 4; ++e) {
        const int idx = t + e * 256;                 // uint4 index within row
        if (idx < 928) {
            const int wo = idx >> 4;                 // pixel 0..57
            const int ch = idx & 15;                 // 8-ci chunk
            uint4 pk = (uint4){0u, 0u, 0u, 0u};
            if (wo >= 1 && wo <= WW_)
                pk = *(const uint4*)&Lx[ch * 456 + (wo - 1) * 8];  // 16B-aligned
            orow[idx] = pk;
        }
    }
}

// ---- main: implicit-GEMM conv — round-0 verified structure, UNchanged
// except the grid is flattened 1D with an XCD-chunked bijective swizzle:
// XCD x (= blockIdx.x & 7, round-robin dispatch) owns logical ids
// [x*196, (x+1)*196): 98 pixel-tiles x both c0 halves adjacent, so the
// 2nd read of each B-panel and neighboring tiles' overlapping im2col rows
// hit the same-XCD L2 (T1; c0-pairing). Math order identical -> bit-identical. ----
__global__ __launch_bounds__(256, 2)
void conv_mfma(const unsigned short* __restrict__ wb,
               const unsigned short* __restrict__ xp,
               const float* __restrict__ bias,
               float* __restrict__ out)
{
    __shared__ __align__(16) unsigned short Asm_[BM * BK];  // 16 KB, rows of 128B
    __shared__ __align__(16) unsigned short Bsm_[BN * BK];  // 16 KB

    const int t = threadIdx.x;

    // bijective XCD-chunked swizzle (NWG % 8 == 0), c0-pair adjacency
    const int logical = (blockIdx.x & 7) * CHUNK + (blockIdx.x >> 3);
    const int pix0 = (logical >> 1) * BN;
    const int c0   = (logical & 1) * BM;

    const int slot = t & 7;
    const int r32  = t >> 3;                 // 0..31
    const int swiz = (slot ^ (r32 & 7)) * 16;

    const char* aBase = (const char*)wb + (size_t)(c0 + r32) * (KTOT * 2) + swiz;
    const char* bBase[4];
    #pragma unroll
    for (int p = 0; p < 4; ++p) {
        const int pix = pix0 + r32 + p * 32;
        const int n   = pix / PLANE;
        const int rem = pix - n * PLANE;
        const int h   = rem / WW_;
        const int w   = rem - h * WW_;
        bBase[p] = (const char*)xp + ((size_t)(n * HP + h) * HP + w) * (CIN * 2) + swiz;
    }

    const int lane = t & 63;
    const int wave = t >> 6;
    const int wm   = (wave & 1) * 64;
    const int wn   = (wave >> 1) * 64;
    const int lr   = lane & 15;
    const int quad = lane >> 4;
    const int rmod = lr & 7;

    f32x4 acc[4][4];
    #pragma unroll
    for (int i = 0; i < 4; ++i)
        #pragma unroll
        for (int j = 0; j < 4; ++j)
            acc[i][j] = (f32x4){0.f, 0.f, 0.f, 0.f};

    char* const asmb = (char*)Asm_;
    char* const bsmb = (char*)Bsm_;

    for (int tap = 0; tap < 9; ++tap) {
        const int toff = ((tap / 3) * HP + (tap % 3)) * (CIN * 2);
        for (int ci0b = 0; ci0b < 256; ci0b += 128) {
            const int abyte = tap * 256 + ci0b;
            #pragma unroll
            for (int p = 0; p < 4; ++p)
                gl_lds16(aBase + (size_t)p * 32 * (KTOT * 2) + abyte, asmb + p * 4096 + t * 16);
            #pragma unroll
            for (int p = 0; p < 4; ++p)
                gl_lds16(bBase[p] + toff + ci0b, bsmb + p * 4096 + t * 16);
            __syncthreads();

            #pragma unroll
            for (int kk = 0; kk < 2; ++kk) {
                bf16x8 af[4], bfr[4];
                #pragma unroll
                for (int i = 0; i < 4; ++i) {
                    const int r = wm + i * 16 + lr;
                    const int phys = ((kk * 4 + quad) ^ rmod) * 16;
                    af[i] = *(const bf16x8*)(asmb + r * 128 + phys);
                }
                #pragma unroll
                for (int j = 0; j < 4; ++j) {
                    const int r = wn + j * 16 + lr;
                    const int phys = ((kk * 4 + quad) ^ rmod) * 16;
                    bfr[j] = *(const bf16x8*)(bsmb + r * 128 + phys);
                }
                #pragma unroll
                for (int i = 0; i < 4; ++i)
                    #pragma unroll
                    for (int j = 0; j < 4; ++j)
                        acc[i][j] = __builtin_amdgcn_mfma_f32_16x16x32_bf16(af[i], bfr[j], acc[i][j], 0, 0, 0);
            }
            __syncthreads();
        }
    }

    #pragma unroll
    for (int j = 0; j < 4; ++j) {
        const int pg    = pix0 + wn + j * 16 + lr;
        const int ni    = pg / PLANE;
        const int inner = pg - ni * PLANE;
        float* op = out + (size_t)ni * (COUT * PLANE) + inner;
        #pragma unroll
        for (int i = 0; i < 4; ++i) {
            const int crow = c0 + wm + i * 16 + quad * 4;
            #pragma unroll
            for (int r = 0; r < 4; ++r)
                op[(size_t)(crow + r) * PLANE] = acc[i][j][r] + bias[crow + r];
        }
    }
}

extern "C" void kernel_launch(void* const* d_in, const int* in_sizes, int n_in,
                              void* d_out, int out_size, void* d_ws, size_t ws_size,
                              hipStream_t stream) {
    const float* in   = (const float*)d_in[0];
    const float* wt   = (const float*)d_in[1];
    const float* bias = (const float*)d_in[2];
    float* out        = (float*)d_out;

    unsigned short* wb = (unsigned short*)((char*)d_ws + WB_OFF);
    unsigned short* xp = (unsigned short*)((char*)d_ws + XP_OFF);

    prep<<<NXROWS + COUT, 256, 0, stream>>>(in, wt, xp, wb);

    conv_mfma<<<dim3(NWG), 256, 0, stream>>>(wb, xp, bias, out);
}